// Round 1
// baseline (1846.366 us; speedup 1.0000x reference)
//
#include <hip/hip_runtime.h>
#include <stdint.h>
#include <stddef.h>

// Row-parallel linear: C[M][N] = A[M][K] * W[N][K]^T + bias
// M = SEQ*BATCH = 8192, N = D_MODEL = 4096, K = D_FF = 16384
#define M_DIM 8192
#define N_DIM 4096
#define K_DIM 16384

#define BM 128
#define BN 128
#define BK 64
#define NTHR 256   // 4 waves, 2x2 wave grid, each wave owns 64x64 output

typedef __attribute__((ext_vector_type(8))) short bf16x8;   // 8 bf16 = 4 VGPRs
typedef __attribute__((ext_vector_type(4))) float f32x4;    // MFMA C/D

#define AS1 __attribute__((address_space(1)))
#define AS3 __attribute__((address_space(3)))

// fp32 -> bf16 round-to-nearest-even (inputs are finite gaussians; no NaN guard)
__device__ __forceinline__ unsigned short f2bf(float f) {
  union { float f; unsigned u; } x; x.f = f;
  unsigned r = x.u + 0x7fffu + ((x.u >> 16) & 1u);
  return (unsigned short)(r >> 16);
}

// ---------------- pass 1: fp32 -> bf16 conversion (memory-bound) --------------
__global__ void cvt_f32_bf16(const float* __restrict__ in,
                             unsigned short* __restrict__ out, long n4) {
  long idx = (long)blockIdx.x * blockDim.x + threadIdx.x;
  long stride = (long)gridDim.x * blockDim.x;
  const float4* in4 = (const float4*)in;
  ushort4* out4 = (ushort4*)out;
  for (long i = idx; i < n4; i += stride) {
    float4 v = in4[i];
    ushort4 o;
    o.x = f2bf(v.x); o.y = f2bf(v.y); o.z = f2bf(v.z); o.w = f2bf(v.w);
    out4[i] = o;
  }
}

// ---------------- pass 2: bf16 MFMA GEMM (m97-style 128x128, BK=64) -----------
// CVT=false: Ap/Wp are pre-converted bf16 (unsigned short) arrays.
// CVT=true : Ap/Wp are the original fp32 arrays; convert during LDS staging.
template<bool CVT>
__global__ __launch_bounds__(NTHR)
void gemm_rowlin(const void* __restrict__ Ap, const void* __restrict__ Wp,
                 const float* __restrict__ bias, float* __restrict__ C) {
  __shared__ __align__(16) unsigned short smA[BM * BK];  // [128][64] row-major, 16 KiB
  __shared__ __align__(16) unsigned short smB[BN * BK];  // [128][64] row-major, 16 KiB

  const int tid  = threadIdx.x;
  const int wave = tid >> 6;
  const int lane = tid & 63;
  const int wr = wave >> 1;      // wave row (0..1)
  const int wc = wave & 1;       // wave col (0..1)

  // XCD-aware bijective swizzle: nwg = 2048, divisible by 8 XCDs.
  const int nbn = N_DIM / BN;                 // 32
  const int nwg = (M_DIM / BM) * nbn;         // 2048
  const int bid = blockIdx.x;
  const int swz = (bid & 7) * (nwg >> 3) + (bid >> 3);
  const int bm = swz / nbn;
  const int bn = swz % nbn;

  f32x4 acc[4][4];
  const f32x4 z = {0.f, 0.f, 0.f, 0.f};
#pragma unroll
  for (int m = 0; m < 4; ++m)
#pragma unroll
    for (int n = 0; n < 4; ++n) acc[m][n] = z;

  const unsigned short* A = (const unsigned short*)Ap;
  const unsigned short* W = (const unsigned short*)Wp;
  const float* Af = (const float*)Ap;
  const float* Wf = (const float*)Wp;

  // staging geometry (CVT=false): one global_load_lds_dwordx4 per wave covers
  // 64 lanes * 16B = 1 KiB = 8 rows of 128B. Wave w covers rows [w*32, w*32+32).
  const int srow = wave * 32;
  const int lr = lane >> 3;          // row within the 8-row chunk
  const int lc = (lane & 7) * 8;     // element column (16B granules)

  for (int kt = 0; kt < K_DIM / BK; ++kt) {
    const int k0 = kt * BK;
    if constexpr (!CVT) {
#pragma unroll
      for (int j = 0; j < 4; ++j) {
        const int row = srow + j * 8;                 // wave-uniform LDS base row
        const unsigned short* ga =
            A + (size_t)(bm * BM + row + lr) * K_DIM + k0 + lc;
        __builtin_amdgcn_global_load_lds((AS1 void*)ga, (AS3 void*)(smA + row * BK),
                                         16, 0, 0);
        const unsigned short* gb =
            W + (size_t)(bn * BN + row + lr) * K_DIM + k0 + lc;
        __builtin_amdgcn_global_load_lds((AS1 void*)gb, (AS3 void*)(smB + row * BK),
                                         16, 0, 0);
      }
    } else {
      // fused conversion: thread t handles half a row (32 floats) of A and W
      const int row2 = tid >> 1;            // 0..127
      const int ch = (tid & 1) * 32;        // column half
      const float* sa = Af + (size_t)(bm * BM + row2) * K_DIM + k0 + ch;
      const float* sb = Wf + (size_t)(bn * BN + row2) * K_DIM + k0 + ch;
      unsigned short* da = smA + row2 * BK + ch;
      unsigned short* db = smB + row2 * BK + ch;
#pragma unroll
      for (int j = 0; j < 8; ++j) {
        float4 v = *(const float4*)(sa + j * 4);
        ushort4 o;
        o.x = f2bf(v.x); o.y = f2bf(v.y); o.z = f2bf(v.z); o.w = f2bf(v.w);
        *(ushort4*)(da + j * 4) = o;
        float4 w = *(const float4*)(sb + j * 4);
        ushort4 p;
        p.x = f2bf(w.x); p.y = f2bf(w.y); p.z = f2bf(w.z); p.w = f2bf(w.w);
        *(ushort4*)(db + j * 4) = p;
      }
    }
    __syncthreads();   // drains vmcnt (global_load_lds) / lgkmcnt before compute

#pragma unroll
    for (int ks = 0; ks < 2; ++ks) {
      bf16x8 af[4], bfr[4];
#pragma unroll
      for (int m = 0; m < 4; ++m)
        af[m] = *(const bf16x8*)(smA + (wr * 64 + m * 16 + (lane & 15)) * BK +
                                 ks * 32 + (lane >> 4) * 8);
#pragma unroll
      for (int n = 0; n < 4; ++n)
        bfr[n] = *(const bf16x8*)(smB + (wc * 64 + n * 16 + (lane & 15)) * BK +
                                  ks * 32 + (lane >> 4) * 8);
#pragma unroll
      for (int m = 0; m < 4; ++m)
#pragma unroll
        for (int n = 0; n < 4; ++n)
          acc[m][n] = __builtin_amdgcn_mfma_f32_16x16x32_bf16(af[m], bfr[n],
                                                              acc[m][n], 0, 0, 0);
    }
    __syncthreads();   // protect LDS before next stage overwrites
  }

  // epilogue: C/D layout (m89): col = lane&15, row = (lane>>4)*4 + j
  const int crow = bm * BM + wr * 64 + ((lane >> 4) << 2);
  const int ccol = bn * BN + wc * 64 + (lane & 15);
#pragma unroll
  for (int n = 0; n < 4; ++n) {
    const float bv = bias[ccol + n * 16];
#pragma unroll
    for (int m = 0; m < 4; ++m) {
      const size_t base = (size_t)(crow + m * 16) * N_DIM + (ccol + n * 16);
#pragma unroll
      for (int j = 0; j < 4; ++j)
        C[base + (size_t)j * N_DIM] = acc[m][n][j] + bv;
    }
  }
}

// ------------------------------ launcher --------------------------------------
extern "C" void kernel_launch(void* const* d_in, const int* in_sizes, int n_in,
                              void* d_out, int out_size, void* d_ws, size_t ws_size,
                              hipStream_t stream) {
  const float* A    = (const float*)d_in[0];   // [8192, 16384] fp32 (S*B rows)
  const float* Wt   = (const float*)d_in[1];   // [4096, 16384] fp32
  const float* bias = (const float*)d_in[2];   // [4096] fp32
  float* out = (float*)d_out;                  // [8192, 4096] fp32

  const size_t elemsA = (size_t)M_DIM * K_DIM;
  const size_t elemsW = (size_t)N_DIM * K_DIM;
  const size_t need = (elemsA + elemsW) * sizeof(unsigned short);  // 384 MiB

  const int ngrid = (M_DIM / BM) * (N_DIM / BN);  // 2048

  if (ws_size >= need) {
    unsigned short* wsA = (unsigned short*)d_ws;
    unsigned short* wsW = wsA + elemsA;
    cvt_f32_bf16<<<2048, 256, 0, stream>>>(A, wsA, (long)(elemsA / 4));
    cvt_f32_bf16<<<2048, 256, 0, stream>>>(Wt, wsW, (long)(elemsW / 4));
    gemm_rowlin<false><<<ngrid, NTHR, 0, stream>>>(wsA, wsW, bias, out);
  } else {
    // workspace too small: fused fp32->bf16 conversion inside the GEMM
    gemm_rowlin<true><<<ngrid, NTHR, 0, stream>>>(A, Wt, bias, out);
  }
}

// Round 2
// 1432.175 us; speedup vs baseline: 1.2892x; 1.2892x over previous
//
#include <hip/hip_runtime.h>
#include <stdint.h>
#include <stddef.h>

// Row-parallel linear: C[M][N] = A[M][K] * W[N][K]^T + bias
// M = SEQ*BATCH = 8192, N = D_MODEL = 4096, K = D_FF = 16384
#define M_DIM 8192
#define N_DIM 4096
#define K_DIM 16384

#define BM 256
#define BN 256
#define BK 64
#define NTHR 512                  // 8 waves: 2 (M) x 4 (N)
#define K_TILES (K_DIM / BK)      // 256

typedef __attribute__((ext_vector_type(8))) short bf16x8;   // 8 bf16 = 4 VGPRs
typedef __attribute__((ext_vector_type(4))) float f32x4;    // MFMA C/D

#define AS1 __attribute__((address_space(1)))
#define AS3 __attribute__((address_space(3)))

__device__ __forceinline__ unsigned short f2bf(float f) {
  union { float f; unsigned u; } x; x.f = f;
  unsigned r = x.u + 0x7fffu + ((x.u >> 16) & 1u);
  return (unsigned short)(r >> 16);
}

// ---------------- pass 1: fp32 -> bf16 conversion (memory-bound) --------------
__global__ void cvt_f32_bf16(const float* __restrict__ in,
                             unsigned short* __restrict__ out, long n4) {
  long idx = (long)blockIdx.x * blockDim.x + threadIdx.x;
  long stride = (long)gridDim.x * blockDim.x;
  const float4* in4 = (const float4*)in;
  ushort4* out4 = (ushort4*)out;
  for (long i = idx; i < n4; i += stride) {
    float4 v = in4[i];
    ushort4 o;
    o.x = f2bf(v.x); o.y = f2bf(v.y); o.z = f2bf(v.z); o.w = f2bf(v.w);
    out4[i] = o;
  }
}

// ---------------- pass 2: 256x256 8-phase bf16 MFMA GEMM ----------------------
// 4 phases per K-tile (BK=64 = 2 MFMA k-slices), double-buffered 128 KiB LDS,
// XOR-swizzled LDS (slot ^= row&7, 16B slots) with pre-swizzled global source,
// counted vmcnt(4) staging pipeline (each wave stages exactly what it reads,
// in consumption order: Aq0, Bq0, Bq1, Aq1 of the NEXT tile).
#define BAR()   __builtin_amdgcn_s_barrier()
#define SCHED0() __builtin_amdgcn_sched_barrier(0)
#define WAIT_LGKM0() do { asm volatile("s_waitcnt lgkmcnt(0)" ::: "memory"); \
                          __builtin_amdgcn_sched_barrier(0); } while (0)

#define MFMA_QUAD(MQ, NP)                                                      \
  do {                                                                         \
    __builtin_amdgcn_s_setprio(1);                                             \
    _Pragma("unroll") for (int mi = 0; mi < 4; ++mi)                           \
      _Pragma("unroll") for (int nn = 0; nn < 2; ++nn)                         \
        _Pragma("unroll") for (int ks = 0; ks < 2; ++ks)                       \
          acc[(MQ)*4 + mi][(NP)*2 + nn] =                                      \
              __builtin_amdgcn_mfma_f32_16x16x32_bf16(                         \
                  af[mi][ks], bf[(NP)*2 + nn][ks],                             \
                  acc[(MQ)*4 + mi][(NP)*2 + nn], 0, 0, 0);                     \
    __builtin_amdgcn_s_setprio(0);                                             \
  } while (0)

__global__ __launch_bounds__(NTHR, 2)
void gemm256(const unsigned short* __restrict__ A,
             const unsigned short* __restrict__ W,
             const float* __restrict__ bias, float* __restrict__ C) {
  __shared__ unsigned short smA[2][BM * BK];   // 2 x 32 KiB
  __shared__ unsigned short smB[2][BN * BK];   // 2 x 32 KiB

  const int tid  = threadIdx.x;
  const int wave = tid >> 6;
  const int lane = tid & 63;
  const int wr = wave >> 2;          // 0..1  (M waves, 128 rows each)
  const int wc = wave & 3;           // 0..3  (N waves, 64 cols each)
  const int g  = lane >> 4;          // frag k-group
  const int xr = (lane & 7) << 4;    // read-side swizzle term (row&7)<<4

  // byte column (pre-swizzled) of frag reads, per k-slice
  int csw[2];
  csw[0] = (g * 16) ^ xr;
  csw[1] = (64 + g * 16) ^ xr;

  // XCD-aware bijective swizzle; nwg = 512 (divisible by 8)
  const int nbn = N_DIM / BN;                  // 16
  const int nwg = (M_DIM / BM) * nbn;          // 512
  const int bid = blockIdx.x;
  const int swz = (bid & 7) * (nwg >> 3) + (bid >> 3);
  const int bm = swz / nbn, bn = swz % nbn;
  const int bmBase = bm * BM, bnBase = bn * BN;

  // per-lane pre-swizzled global source offset (elements):
  // lane l -> dest row row0+(l>>3), slot l&7 holds global slot (l&7)^((l>>3)&7)
  const size_t laneOff = (size_t)(lane >> 3) * K_DIM +
                         (size_t)(((lane & 7) ^ ((lane >> 3) & 7)) * 8);

  const unsigned short* aSrc =
      A + (size_t)(bmBase + wr * 128 + wc * 16) * K_DIM + laneOff;
  const unsigned short* bSrc =
      W + (size_t)(bnBase + wc * 64 + wr * 16) * K_DIM + laneOff;

  f32x4 acc[8][4];
  const f32x4 z = {0.f, 0.f, 0.f, 0.f};
#pragma unroll
  for (int m = 0; m < 8; ++m)
#pragma unroll
    for (int n = 0; n < 4; ++n) acc[m][n] = z;

  bf16x8 af[4][2];   // current m-quad fragments
  bf16x8 bf[4][2];   // all 4 n fragments (n0-1 loaded ph1, n2-3 ph2)

  // ---- staging helpers (each wave stages exactly the data it reads) ----
  auto stageA = [&](int mq, int nxt, size_t kOff) {
#pragma unroll
    for (int j = 0; j < 2; ++j) {
      const unsigned short* src = aSrc + (size_t)(mq * 64 + j * 8) * K_DIM + kOff;
      unsigned short* dst = &smA[nxt][(wr * 128 + mq * 64 + wc * 16 + j * 8) * BK];
      __builtin_amdgcn_global_load_lds((AS1 void*)src, (AS3 void*)dst, 16, 0, 0);
    }
  };
  auto stageB = [&](int h, int nxt, size_t kOff) {
#pragma unroll
    for (int j = 0; j < 2; ++j) {
      const unsigned short* src = bSrc + (size_t)(h * 32 + j * 8) * K_DIM + kOff;
      unsigned short* dst = &smB[nxt][(wc * 64 + h * 32 + wr * 16 + j * 8) * BK];
      __builtin_amdgcn_global_load_lds((AS1 void*)src, (AS3 void*)dst, 16, 0, 0);
    }
  };
  auto readA = [&](const char* aRd, int mq) {
#pragma unroll
    for (int mi = 0; mi < 4; ++mi)
#pragma unroll
      for (int ks = 0; ks < 2; ++ks)
        af[mi][ks] = *(const bf16x8*)(aRd + (mq * 64 + mi * 16) * 128 + csw[ks]);
  };
  auto readB = [&](const char* bRd, int np) {
#pragma unroll
    for (int nn = 0; nn < 2; ++nn)
#pragma unroll
      for (int ks = 0; ks < 2; ++ks)
        bf[np * 2 + nn][ks] =
            *(const bf16x8*)(bRd + (np * 32 + nn * 16) * 128 + csw[ks]);
  };

  // ---- prologue: stage tile 0 into buf 0, drain once ----
  stageA(0, 0, 0); stageB(0, 0, 0); stageB(1, 0, 0); stageA(1, 0, 0);
  asm volatile("s_waitcnt vmcnt(0)" ::: "memory");
  BAR(); SCHED0();

  int cur = 0;
  size_t kOff = BK;
  for (int t = 0; t < K_TILES - 1; ++t) {
    const int nxt = cur ^ 1;
    const char* aRd = (const char*)&smA[cur][0] + (wr * 128 + (lane & 15)) * 128;
    const char* bRd = (const char*)&smB[cur][0] + (wc * 64 + (lane & 15)) * 128;

    // phase 1: frags for quad(m0-3 x n0-1); stage Aq0(next); wait completes Bq1(cur)
    readA(aRd, 0); readB(bRd, 0);
    stageA(0, nxt, kOff);
    asm volatile("s_waitcnt vmcnt(4)" ::: "memory");
    BAR(); SCHED0(); WAIT_LGKM0();
    MFMA_QUAD(0, 0);
    BAR(); SCHED0();

    // phase 2: frags n2-3; stage Bq0(next); wait completes Aq1(cur)
    readB(bRd, 1);
    stageB(0, nxt, kOff);
    asm volatile("s_waitcnt vmcnt(4)" ::: "memory");
    BAR(); SCHED0(); WAIT_LGKM0();
    MFMA_QUAD(0, 1);
    BAR(); SCHED0();

    // phase 3: frags m4-7; stage Bq1(next); no wait needed
    readA(aRd, 1);
    stageB(1, nxt, kOff);
    BAR(); SCHED0(); WAIT_LGKM0();
    MFMA_QUAD(1, 1);
    BAR(); SCHED0();

    // phase 4: reuse bf[n0-1]; stage Aq1(next); wait completes Aq0+Bq0(next)
    stageA(1, nxt, kOff);
    asm volatile("s_waitcnt vmcnt(4)" ::: "memory");
    BAR(); SCHED0();
    MFMA_QUAD(1, 0);
    BAR(); SCHED0();

    cur = nxt; kOff += BK;
  }

  // ---- final tile: no staging; drain 2 -> 0 ----
  {
    const char* aRd = (const char*)&smA[cur][0] + (wr * 128 + (lane & 15)) * 128;
    const char* bRd = (const char*)&smB[cur][0] + (wc * 64 + (lane & 15)) * 128;

    readA(aRd, 0); readB(bRd, 0);
    asm volatile("s_waitcnt vmcnt(2)" ::: "memory");
    BAR(); SCHED0(); WAIT_LGKM0();
    MFMA_QUAD(0, 0);
    BAR(); SCHED0();

    readB(bRd, 1);
    asm volatile("s_waitcnt vmcnt(0)" ::: "memory");
    BAR(); SCHED0(); WAIT_LGKM0();
    MFMA_QUAD(0, 1);
    BAR(); SCHED0();

    readA(aRd, 1);
    BAR(); SCHED0(); WAIT_LGKM0();
    MFMA_QUAD(1, 1);
    BAR(); SCHED0();

    MFMA_QUAD(1, 0);
  }

  // ---- epilogue: C = acc + bias. C/D layout: col=lane&15, row=(lane>>4)*4+j
  const int crow0 = bmBase + wr * 128 + ((lane >> 4) << 2);
  const int ccol0 = bnBase + wc * 64 + (lane & 15);
#pragma unroll
  for (int n = 0; n < 4; ++n) {
    const float bv = bias[ccol0 + n * 16];
#pragma unroll
    for (int mi = 0; mi < 8; ++mi) {
      const size_t base = (size_t)(crow0 + mi * 16) * N_DIM + (ccol0 + n * 16);
#pragma unroll
      for (int j = 0; j < 4; ++j)
        C[base + (size_t)j * N_DIM] = acc[mi][n][j] + bv;
    }
  }
}

// ---------------- fallback: fused-cvt 128x128 GEMM (ws too small) -------------
__global__ __launch_bounds__(256)
void gemm_fallback(const float* __restrict__ Af, const float* __restrict__ Wf,
                   const float* __restrict__ bias, float* __restrict__ C) {
  __shared__ __align__(16) unsigned short sA[128 * 64];
  __shared__ __align__(16) unsigned short sB[128 * 64];
  const int tid = threadIdx.x, wave = tid >> 6, lane = tid & 63;
  const int wr = wave >> 1, wc = wave & 1;
  const int nbn = N_DIM / 128, nwg = (M_DIM / 128) * nbn;
  const int swz = (blockIdx.x & 7) * (nwg >> 3) + (blockIdx.x >> 3);
  const int bm = swz / nbn, bn = swz % nbn;
  f32x4 acc[4][4];
  const f32x4 z = {0.f, 0.f, 0.f, 0.f};
#pragma unroll
  for (int m = 0; m < 4; ++m)
#pragma unroll
    for (int n = 0; n < 4; ++n) acc[m][n] = z;
  for (int kt = 0; kt < K_DIM / 64; ++kt) {
    const int k0 = kt * 64;
    const int row2 = tid >> 1, ch = (tid & 1) * 32;
    const float* sa = Af + (size_t)(bm * 128 + row2) * K_DIM + k0 + ch;
    const float* sb = Wf + (size_t)(bn * 128 + row2) * K_DIM + k0 + ch;
    unsigned short* da = sA + row2 * 64 + ch;
    unsigned short* db = sB + row2 * 64 + ch;
#pragma unroll
    for (int j = 0; j < 8; ++j) {
      float4 v = *(const float4*)(sa + j * 4);
      ushort4 o; o.x = f2bf(v.x); o.y = f2bf(v.y); o.z = f2bf(v.z); o.w = f2bf(v.w);
      *(ushort4*)(da + j * 4) = o;
      float4 w = *(const float4*)(sb + j * 4);
      ushort4 p; p.x = f2bf(w.x); p.y = f2bf(w.y); p.z = f2bf(w.z); p.w = f2bf(w.w);
      *(ushort4*)(db + j * 4) = p;
    }
    __syncthreads();
#pragma unroll
    for (int ks = 0; ks < 2; ++ks) {
      bf16x8 a4[4], b4[4];
#pragma unroll
      for (int m = 0; m < 4; ++m)
        a4[m] = *(const bf16x8*)(sA + (wr * 64 + m * 16 + (lane & 15)) * 64 +
                                 ks * 32 + (lane >> 4) * 8);
#pragma unroll
      for (int n = 0; n < 4; ++n)
        b4[n] = *(const bf16x8*)(sB + (wc * 64 + n * 16 + (lane & 15)) * 64 +
                                 ks * 32 + (lane >> 4) * 8);
#pragma unroll
      for (int m = 0; m < 4; ++m)
#pragma unroll
        for (int n = 0; n < 4; ++n)
          acc[m][n] = __builtin_amdgcn_mfma_f32_16x16x32_bf16(a4[m], b4[n],
                                                              acc[m][n], 0, 0, 0);
    }
    __syncthreads();
  }
  const int crow = bm * 128 + wr * 64 + ((lane >> 4) << 2);
  const int ccol = bn * 128 + wc * 64 + (lane & 15);
#pragma unroll
  for (int n = 0; n < 4; ++n) {
    const float bv = bias[ccol + n * 16];
#pragma unroll
    for (int m = 0; m < 4; ++m) {
      const size_t base = (size_t)(crow + m * 16) * N_DIM + (ccol + n * 16);
#pragma unroll
      for (int j = 0; j < 4; ++j) C[base + (size_t)j * N_DIM] = acc[m][n][j] + bv;
    }
  }
}

// ------------------------------ launcher --------------------------------------
extern "C" void kernel_launch(void* const* d_in, const int* in_sizes, int n_in,
                              void* d_out, int out_size, void* d_ws, size_t ws_size,
                              hipStream_t stream) {
  const float* A    = (const float*)d_in[0];   // [8192, 16384] fp32
  const float* Wt   = (const float*)d_in[1];   // [4096, 16384] fp32
  const float* bias = (const float*)d_in[2];   // [4096] fp32
  float* out = (float*)d_out;                  // [8192, 4096] fp32

  const size_t elemsA = (size_t)M_DIM * K_DIM;
  const size_t elemsW = (size_t)N_DIM * K_DIM;
  const size_t need = (elemsA + elemsW) * sizeof(unsigned short);  // 384 MiB

  if (ws_size >= need) {
    unsigned short* wsA = (unsigned short*)d_ws;
    unsigned short* wsW = wsA + elemsA;
    cvt_f32_bf16<<<2048, 256, 0, stream>>>(A, wsA, (long)(elemsA / 4));
    cvt_f32_bf16<<<2048, 256, 0, stream>>>(Wt, wsW, (long)(elemsW / 4));
    const int ngrid = (M_DIM / BM) * (N_DIM / BN);  // 512
    gemm256<<<ngrid, NTHR, 0, stream>>>(wsA, wsW, bias, out);
  } else {
    const int ngrid = (M_DIM / 128) * (N_DIM / 128);
    gemm_fallback<<<ngrid, 256, 0, stream>>>(A, Wt, bias, out);
  }
}